// Round 14
// baseline (222.999 us; speedup 1.0000x reference)
//
#include <hip/hip_runtime.h>
#include <hip/hip_bf16.h>

#define NB 16
#define SEQ 2048
#define EDIM 256

typedef __attribute__((ext_vector_type(16))) float f32x16;
typedef __attribute__((ext_vector_type(4)))  float f32x4;
typedef __attribute__((ext_vector_type(8)))  short short8;

static __device__ __forceinline__ ushort f2bf(float f) {
    uint32_t u = __float_as_uint(f);
    uint32_t r = (u + 0x7fffu + ((u >> 16) & 1u)) >> 16;
    return (ushort)r;
}
static __device__ __forceinline__ float bf2f(ushort h) {
    return __uint_as_float(((uint32_t)h) << 16);
}
// async global->LDS, 16 bytes per lane; LDS dest wave-uniform, global src per-lane.
static __device__ __forceinline__ void gll16(const ushort* g, ushort* l) {
    __builtin_amdgcn_global_load_lds(
        (const __attribute__((address_space(1))) uint32_t*)g,
        (__attribute__((address_space(3))) uint32_t*)l,
        16, 0, 0);
}
// raw barrier: lgkm-only wait, never drains in-flight vmem stores
static __device__ __forceinline__ void lgkm_barrier() {
    asm volatile("s_waitcnt lgkmcnt(0)" ::: "memory");
    __builtin_amdgcn_sched_barrier(0);
    __builtin_amdgcn_s_barrier();
    asm volatile("" ::: "memory");
}

// Kernel 1: fp32 -> bf16 in K-MAJOR PANEL layout xb[b][ks][t][j] (ks=e>>4,
// j=e&15), plus per-row sum of squares of the bf16-rounded values (distance
// diagonal cancels exactly against the fp32-accumulated MFMA gram).
__global__ void prep_kernel(const float* __restrict__ x,
                            ushort* __restrict__ xb,
                            float* __restrict__ sq) {
    __shared__ ushort sh[4][256];
    const int tid  = threadIdx.x;
    const int r    = tid >> 6;
    const int lane = tid & 63;
    const int grow = blockIdx.x * 4;
    const int row  = grow + r;

    const f32x4* xp = reinterpret_cast<const f32x4*>(x + (size_t)row * EDIM + lane * 4);
    const f32x4 v = __builtin_nontemporal_load(xp);
    ushort h0 = f2bf(v.x), h1 = f2bf(v.y), h2 = f2bf(v.z), h3 = f2bf(v.w);
    ushort4 h; h.x = h0; h.y = h1; h.z = h2; h.w = h3;
    *reinterpret_cast<ushort4*>(&sh[r][lane * 4]) = h;

    const float fx = bf2f(h0), fy = bf2f(h1), fz = bf2f(h2), fw = bf2f(h3);
    float s = fx * fx + fy * fy + fz * fz + fw * fw;
    #pragma unroll
    for (int m = 1; m < 64; m <<= 1) s += __shfl_xor(s, m);
    if (lane == 0) sq[row] = s;

    __syncthreads();

    const int b   = grow >> 11;
    const int t0  = grow & 2047;
    const int ksx = tid >> 4;
    const int idx = tid & 15;
    const int r2  = idx >> 2;
    const int j   = (idx & 3) * 4;
    ushort4 o = *reinterpret_cast<ushort4*>(&sh[r2][ksx * 16 + j]);
    *reinterpret_cast<ushort4*>(xb + (size_t)b * SEQ * EDIM
                                   + (size_t)ksx * SEQ * 16
                                   + (size_t)(t0 + r2) * 16 + j) = o;
}

// Kernel 2: fused gram-GEMM + one-pass softmax, 4 row-blocks per WG.
// NEW vs R12: the store phase of row-block i is HIDDEN inside the K-loop of
// row-block i+1. Epilogue deposits scaled probs as bf16 into Tr32[32][2048]
// (128 KB LDS); during the next K-loop each wave drains its own 2 rows, one
// 1KB plain dwordx4 burst per ks (ds_read_b64 + unpack). No barriers in the
// K-loop (waves read only rows they own). A-panel single-buffered (16 KB).
__global__ __launch_bounds__(1024, 4) void sims_main(
        const ushort* __restrict__ xb,
        const float*  __restrict__ sq,
        float* __restrict__ out) {
    __shared__ __align__(16) ushort Ab[16 * 512];    // 16 KB A panel
    __shared__ __align__(16) ushort Tr32[32][2048];  // 128 KB bf16 out buffer
    __shared__ float red[32][17];
    __shared__ float inv_s[32];

    const int b    = blockIdx.x;        // batch -> XCD = flat%8 = b%8
    const int g    = blockIdx.y;        // rows [g*128,(g+1)*128)
    const int tid  = threadIdx.x;
    const int wave = tid >> 6;          // 0..15
    const int lane = tid & 63;
    const int l31  = lane & 31;
    const int hi   = lane >> 5;

    const ushort* xbB = xb + (size_t)b * SEQ * EDIM;
    const float*  sqB = sq + b * SEQ;
    float* outB = out + (size_t)b * SEQ * SEQ;

    const int colw = wave * 128;
    const ushort* bbase = xbB + ((size_t)colw + l31) * 16 + hi * 8;
    const int gl  = lane ^ ((lane >> 3) & 7);       // A-stage src chunk swizzle
    const int r6  = l31 * 2 + hi;
    const int pr6 = r6 ^ ((r6 >> 3) & 7);           // swizzled A read chunk

    constexpr float kC   = (float)(-1.4426950408889634 / 13.544);  // -log2(e)/T
    constexpr float m2kC = -2.0f * kC;
    float kcc[4];
    #pragma unroll
    for (int cb = 0; cb < 4; ++cb) kcc[cb] = kC * sqB[colw + cb * 32 + l31];

    // prologue: stage A panel for row-block 0
    gll16(xbB + (size_t)wave * (SEQ * 16) + ((g * 4 + 0) * 32 + (gl >> 1)) * 16 + (gl & 1) * 8,
          Ab + wave * 512);

    int prev_base = 0;                   // row_base of the block held in Tr32
    const int row2base = 2 * wave;       // this wave drains rows 2w, 2w+1

    #pragma unroll 1
    for (int rb = 0; rb < 4; ++rb) {
        // A panel ready + prev deposits visible to all waves
        asm volatile("s_waitcnt vmcnt(0) lgkmcnt(0)" ::: "memory");
        __builtin_amdgcn_sched_barrier(0);
        __builtin_amdgcn_s_barrier();
        __builtin_amdgcn_sched_barrier(0);

        const int row_base = (g * 4 + rb) * 32;

        f32x16 acc[4];
        #pragma unroll
        for (int cb = 0; cb < 4; ++cb) acc[cb] = (f32x16)0.0f;

        // ---- K-loop with one drain-slot per ks (stores prev block) ----
        #pragma unroll
        for (int ks = 0; ks < 16; ++ks) {
            const ushort* bks = bbase + (size_t)ks * (SEQ * 16);
            short8 bv[4];
            #pragma unroll
            for (int cb = 0; cb < 4; ++cb)
                bv[cb] = *reinterpret_cast<const short8*>(bks + cb * 512);
            const short8 a = *reinterpret_cast<const short8*>(Ab + ks * 512 + pr6 * 8);
            #pragma unroll
            for (int cb = 0; cb < 4; ++cb)
                acc[cb] = __builtin_amdgcn_mfma_f32_32x32x16_bf16(a, bv[cb], acc[cb], 0, 0, 0);
            if (rb > 0) {                // drain slot: 1 KB contiguous burst
                const int row2 = row2base + (ks >> 3);   // own rows only
                const int seg  = ks & 7;
                const uint32_t* tp = reinterpret_cast<const uint32_t*>(
                    &Tr32[row2][seg * 256 + lane * 4]);
                const uint32_t w01 = tp[0], w23 = tp[1];
                f32x4 v;
                v.x = __uint_as_float(w01 << 16);
                v.y = __uint_as_float(w01 & 0xffff0000u);
                v.z = __uint_as_float(w23 << 16);
                v.w = __uint_as_float(w23 & 0xffff0000u);
                *reinterpret_cast<f32x4*>(
                    outB + (size_t)(prev_base + row2) * SEQ + seg * 256 + lane * 4) = v;
            }
        }

        // ---- epilogue: exp(-dist/T), full-row sums ----
        float part[16];
        #pragma unroll
        for (int r = 0; r < 16; ++r) {
            const float kcr = kC * sqB[row_base + (r & 3) + 8 * (r >> 2) + 4 * hi];
            float p = 0.0f;
            #pragma unroll
            for (int cb = 0; cb < 4; ++cb) {
                const float e = exp2f(fmaf(m2kC, acc[cb][r], kcr + kcc[cb]));
                acc[cb][r] = e;
                p += e;
            }
            part[r] = p;
        }
        #pragma unroll
        for (int r = 0; r < 16; ++r) {
            float p = part[r];
            p += __shfl_xor(p, 1);
            p += __shfl_xor(p, 2);
            p += __shfl_xor(p, 4);
            p += __shfl_xor(p, 8);
            p += __shfl_xor(p, 16);
            part[r] = p;
        }
        if (l31 == 0) {
            #pragma unroll
            for (int r = 0; r < 16; ++r) {
                const int lrow = (r & 3) + 8 * (r >> 2) + 4 * hi;
                red[lrow][wave] = part[r];
            }
        }
        lgkm_barrier();                  // also: all drain-slot Tr32 reads done
        if (tid < 32) {
            float s = 0.0f;
            #pragma unroll
            for (int w = 0; w < 16; ++w) s += red[tid][w];
            inv_s[tid] = 1.0f / s;
        }
        lgkm_barrier();

        // ---- deposit: scale + bf16 into Tr32 (frees acc) ----
        #pragma unroll
        for (int r = 0; r < 16; ++r) {
            const int lrow = (r & 3) + 8 * (r >> 2) + 4 * hi;
            const float scale = inv_s[lrow];
            #pragma unroll
            for (int cb = 0; cb < 4; ++cb)
                Tr32[lrow][colw + cb * 32 + l31] = f2bf(acc[cb][r] * scale);
        }

        // stage next block's A panel (Ab free: K-loop done)
        if (rb < 3) {
            gll16(xbB + (size_t)wave * (SEQ * 16)
                      + ((g * 4 + rb + 1) * 32 + (gl >> 1)) * 16 + (gl & 1) * 8,
                  Ab + wave * 512);
        }
        prev_base = row_base;
    }

    // ---- tail: drain last block from Tr32 ----
    lgkm_barrier();                      // deposits visible
    #pragma unroll
    for (int s = 0; s < 16; ++s) {
        const int row2 = row2base + (s >> 3);
        const int seg  = s & 7;
        const uint32_t* tp = reinterpret_cast<const uint32_t*>(
            &Tr32[row2][seg * 256 + lane * 4]);
        const uint32_t w01 = tp[0], w23 = tp[1];
        f32x4 v;
        v.x = __uint_as_float(w01 << 16);
        v.y = __uint_as_float(w01 & 0xffff0000u);
        v.z = __uint_as_float(w23 << 16);
        v.w = __uint_as_float(w23 & 0xffff0000u);
        *reinterpret_cast<f32x4*>(
            outB + (size_t)(prev_base + row2) * SEQ + seg * 256 + lane * 4) = v;
    }
}

extern "C" void kernel_launch(void* const* d_in, const int* in_sizes, int n_in,
                              void* d_out, int out_size, void* d_ws, size_t ws_size,
                              hipStream_t stream) {
    (void)in_sizes; (void)n_in; (void)out_size; (void)ws_size;
    const float* x = (const float*)d_in[0];
    float* out = (float*)d_out;

    ushort* xb = (ushort*)d_ws;                                       // 16 MB bf16, k-major panels
    float*  sq = (float*)((char*)d_ws + (size_t)NB * SEQ * EDIM * 2); // 128 KB row norms

    prep_kernel<<<NB * SEQ / 4, 256, 0, stream>>>(x, xb, sq);

    dim3 grid(NB, 16);   // x = batch: flat%8 == batch%8 -> XCD locality; 256 WGs = 1/CU
    sims_main<<<grid, 1024, 0, stream>>>(xb, sq, out);
}

// Round 15
// 149.490 us; speedup vs baseline: 1.4917x; 1.4917x over previous
//
#include <hip/hip_runtime.h>
#include <hip/hip_bf16.h>

#define NB 16
#define SEQ 2048
#define EDIM 256

typedef __attribute__((ext_vector_type(16))) int   i32x16;
typedef __attribute__((ext_vector_type(4)))  int   int4v;
typedef __attribute__((ext_vector_type(4)))  float f32x4;
typedef unsigned char uchar;

// async global->LDS, 16 bytes per lane; LDS dest wave-uniform, global src per-lane.
static __device__ __forceinline__ void gll16(const uchar* g, uchar* l) {
    __builtin_amdgcn_global_load_lds(
        (const __attribute__((address_space(1))) uint32_t*)g,
        (__attribute__((address_space(3))) uint32_t*)l,
        16, 0, 0);
}
// raw barrier: lgkm-only wait, never drains in-flight vmem stores
static __device__ __forceinline__ void lgkm_barrier() {
    asm volatile("s_waitcnt lgkmcnt(0)" ::: "memory");
    __builtin_amdgcn_sched_barrier(0);
    __builtin_amdgcn_s_barrier();
    asm volatile("" ::: "memory");
}

// Kernel 1: fp32 -> int8 (q = round(16*x), |q| <= ~90: no clipping for N(0,1))
// in K-MAJOR PANEL layout xq[b][ks][t][j], ks = e>>5, j = e&31 (32 i8 = 32 B
// per (ks,t)), plus per-row integer sum of squares sqi = sum(q^2) (exact i32;
// distance diagonal cancels EXACTLY against the i32 MFMA gram).
__global__ void prep_kernel(const float* __restrict__ x,
                            uchar* __restrict__ xq,
                            int* __restrict__ sqi) {
    __shared__ uint32_t sh[4][64];
    const int tid  = threadIdx.x;
    const int r    = tid >> 6;
    const int lane = tid & 63;
    const int grow = blockIdx.x * 4;
    const int row  = grow + r;

    const f32x4* xp = reinterpret_cast<const f32x4*>(x + (size_t)row * EDIM + lane * 4);
    const f32x4 v = __builtin_nontemporal_load(xp);
    int q0 = min(max(__float2int_rn(v.x * 16.0f), -127), 127);
    int q1 = min(max(__float2int_rn(v.y * 16.0f), -127), 127);
    int q2 = min(max(__float2int_rn(v.z * 16.0f), -127), 127);
    int q3 = min(max(__float2int_rn(v.w * 16.0f), -127), 127);
    sh[r][lane] = (uint32_t)(q0 & 255) | ((uint32_t)(q1 & 255) << 8)
                | ((uint32_t)(q2 & 255) << 16) | ((uint32_t)(q3 & 255) << 24);

    int s = q0 * q0 + q1 * q1 + q2 * q2 + q3 * q3;
    #pragma unroll
    for (int m = 1; m < 64; m <<= 1) s += __shfl_xor(s, m);
    if (lane == 0) sqi[row] = s;

    __syncthreads();

    const int b   = grow >> 11;
    const int t0  = grow & 2047;
    const int ksx = tid >> 5;           // 0..7
    const int idx = tid & 31;
    const int r2  = idx >> 3;           // row within the 4
    const int jj  = idx & 7;            // word within 32-byte k-chunk
    const uint32_t o = sh[r2][ksx * 8 + jj];
    *reinterpret_cast<uint32_t*>(xq + (size_t)b * SEQ * EDIM
                                    + (size_t)ksx * SEQ * 32
                                    + (size_t)(t0 + r2) * 32 + jj * 4) = o;
}

// Kernel 2: fused int8-gram GEMM + one-pass softmax (R12 structure verbatim;
// dtype shrunk to i8). 4 row-blocks per WG, grid (16,16) = 1 WG/CU.
// K-loop: 8 iters of mfma_i32_32x32x32_i8; B frags direct from global
// (k-major panels, 1KB/wave dwordx4 coalesced); A panel dbuf in LDS (2x8KB).
// dist_int = sqi_r + sqi_c - 2*gram is EXACT in i32 -> diagonal exactly 0.
// Stores: separate transpose-burst phase, PLAIN stores (R12 lesson), counted
// vmcnt(16) at block top keeps prev stores in flight under next K-loop;
// NEVER store inside the K-loop (R8/R13 lesson).
__global__ __launch_bounds__(1024, 4) void sims_main(
        const uchar* __restrict__ xq,
        const int*   __restrict__ sqi,
        float* __restrict__ out) {
    __shared__ __align__(16) uchar Ab[2][8192];       // 2 x 8 KB A panels
    __shared__ __align__(16) float Tr[8][2048];       // 64 KB transpose buffer
    __shared__ float red[32][17];
    __shared__ float inv_s[32];

    const int b    = blockIdx.x;        // batch -> XCD = flat%8 = b%8
    const int g    = blockIdx.y;        // rows [g*128,(g+1)*128)
    const int tid  = threadIdx.x;
    const int wave = tid >> 6;          // 0..15
    const int lane = tid & 63;
    const int l31  = lane & 31;
    const int hi   = lane >> 5;

    const uchar* xqB = xq + (size_t)b * SEQ * EDIM;
    const int*   sqB = sqi + b * SEQ;
    float* outB = out + (size_t)b * SEQ * SEQ;

    const int colw = wave * 128;
    const uchar* bbase = xqB + ((size_t)colw + l31) * 32 + hi * 16;
    const int gl  = lane ^ ((lane >> 3) & 7);       // A-stage src chunk swizzle
    const int r6  = l31 * 2 + hi;
    const int pr6 = r6 ^ ((r6 >> 3) & 7);           // swizzled A read chunk

    // exponent constants: dist_q = dist * 256 (S=16); expo = kC256*(sqr+sqc) + kQ*gram
    constexpr float kC256 = (float)(-1.4426950408889634 / (13.544 * 256.0));
    constexpr float kQ    = (float)( 2.0 * 1.4426950408889634 / (13.544 * 256.0));
    float kcc[4];
    #pragma unroll
    for (int cb = 0; cb < 4; ++cb) kcc[cb] = kC256 * (float)sqB[colw + cb * 32 + l31];

    // prologue: stage A panel for row-block 0 (waves 0..7, one ks-slice each)
    if (wave < 8) {
        gll16(xqB + (size_t)wave * (SEQ * 32) + ((size_t)((g * 4 + 0) * 32 + (gl >> 1))) * 32 + (gl & 1) * 16,
              &Ab[0][wave * 1024]);
    }

    const int lr8r = wave >> 1;          // row within 8-row chunk this wave stores
    const int half = wave & 1;           // which 4KB half of the row

    #pragma unroll 1
    for (int rb = 0; rb < 4; ++rb) {
        // A-panel ready; prev row-block's <=16 stores may stay in flight.
        if (rb == 0) { asm volatile("s_waitcnt vmcnt(0)" ::: "memory"); }
        else         { asm volatile("s_waitcnt vmcnt(16)" ::: "memory"); }
        __builtin_amdgcn_sched_barrier(0);
        __builtin_amdgcn_s_barrier();
        __builtin_amdgcn_sched_barrier(0);

        const int row_base = (g * 4 + rb) * 32;
        const uchar* AbC = &Ab[rb & 1][0];

        i32x16 acc[4];
        #pragma unroll
        for (int cb = 0; cb < 4; ++cb) acc[cb] = (i32x16)0;

        #pragma unroll
        for (int ks = 0; ks < 8; ++ks) {
            const uchar* bks = bbase + (size_t)ks * (SEQ * 32);
            int4v bv[4];
            #pragma unroll
            for (int cb = 0; cb < 4; ++cb)
                bv[cb] = *reinterpret_cast<const int4v*>(bks + cb * 1024);
            const int4v a = *reinterpret_cast<const int4v*>(AbC + ks * 1024 + pr6 * 16);
            #pragma unroll
            for (int cb = 0; cb < 4; ++cb)
                acc[cb] = __builtin_amdgcn_mfma_i32_32x32x32_i8(a, bv[cb], acc[cb], 0, 0, 0);
        }

        // prefetch next row-block's A panel into the other buffer
        if (rb < 3 && wave < 8) {
            gll16(xqB + (size_t)wave * (SEQ * 32)
                      + ((size_t)((g * 4 + rb + 1) * 32 + (gl >> 1))) * 32 + (gl & 1) * 16,
                  &Ab[(rb + 1) & 1][wave * 1024]);
        }

        // ---- epilogue: exp2(kC256*(sqr+sqc) + kQ*gram), full-row sums ----
        float part[16];
        #pragma unroll
        for (int r = 0; r < 16; ++r) {
            const float kcr = kC256 * (float)sqB[row_base + (r & 3) + 8 * (r >> 2) + 4 * hi];
            float p = 0.0f;
            #pragma unroll
            for (int cb = 0; cb < 4; ++cb) {
                const float e = exp2f(fmaf(kQ, (float)acc[cb][r], kcr + kcc[cb]));
                acc[cb][r] = __float_as_int(e);
                p += e;
            }
            part[r] = p;
        }
        #pragma unroll
        for (int r = 0; r < 16; ++r) {
            float p = part[r];
            p += __shfl_xor(p, 1);
            p += __shfl_xor(p, 2);
            p += __shfl_xor(p, 4);
            p += __shfl_xor(p, 8);
            p += __shfl_xor(p, 16);
            part[r] = p;
        }
        if (l31 == 0) {
            #pragma unroll
            for (int r = 0; r < 16; ++r) {
                const int lrow = (r & 3) + 8 * (r >> 2) + 4 * hi;
                red[lrow][wave] = part[r];
            }
        }
        lgkm_barrier();
        if (tid < 32) {
            float s = 0.0f;
            #pragma unroll
            for (int w = 0; w < 16; ++w) s += red[tid][w];
            inv_s[tid] = 1.0f / s;
        }
        lgkm_barrier();

        // ---- transpose-burst store: 4 chunks x 8 rows through LDS ----
        #pragma unroll 1
        for (int c = 0; c < 4; ++c) {
            #pragma unroll
            for (int rr = 0; rr < 4; ++rr) {
                const int r    = 4 * c + rr;
                const int lrow = rr + 8 * c + 4 * hi;
                const int lr8  = rr + 4 * hi;
                const float scale = inv_s[lrow];
                #pragma unroll
                for (int cb = 0; cb < 4; ++cb)
                    Tr[lr8][colw + cb * 32 + l31] = __int_as_float(acc[cb][r]) * scale;
            }
            lgkm_barrier();
            float* orow = outB + (size_t)(row_base + 8 * c + lr8r) * SEQ + half * 1024;
            #pragma unroll
            for (int j = 0; j < 4; ++j) {
                const f32x4 v = *reinterpret_cast<const f32x4*>(
                    &Tr[lr8r][half * 1024 + j * 256 + lane * 4]);
                *reinterpret_cast<f32x4*>(&orow[j * 256 + lane * 4]) = v;  // plain store
            }
            lgkm_barrier();              // Tr reads complete; stores keep flying
        }
    }
}

extern "C" void kernel_launch(void* const* d_in, const int* in_sizes, int n_in,
                              void* d_out, int out_size, void* d_ws, size_t ws_size,
                              hipStream_t stream) {
    (void)in_sizes; (void)n_in; (void)out_size; (void)ws_size;
    const float* x = (const float*)d_in[0];
    float* out = (float*)d_out;

    uchar* xq  = (uchar*)d_ws;                                  // 8 MB int8, k-major panels
    int*   sqi = (int*)((char*)d_ws + (size_t)NB * SEQ * EDIM); // 128 KB integer row norms

    prep_kernel<<<NB * SEQ / 4, 256, 0, stream>>>(x, xq, sqi);

    dim3 grid(NB, 16);   // x = batch: flat%8 == batch%8 -> XCD locality; 256 WGs = 1/CU
    sims_main<<<grid, 1024, 0, stream>>>(xq, sqi, out);
}

// Round 16
// 128.863 us; speedup vs baseline: 1.7305x; 1.1601x over previous
//
#include <hip/hip_runtime.h>
#include <hip/hip_bf16.h>

#define NB 16
#define SEQ 2048
#define EDIM 256

typedef __attribute__((ext_vector_type(16))) float f32x16;
typedef __attribute__((ext_vector_type(4)))  float f32x4;
typedef __attribute__((ext_vector_type(8)))  short short8;

static __device__ __forceinline__ ushort f2bf(float f) {
    uint32_t u = __float_as_uint(f);
    uint32_t r = (u + 0x7fffu + ((u >> 16) & 1u)) >> 16;
    return (ushort)r;
}
static __device__ __forceinline__ float bf2f(ushort h) {
    return __uint_as_float(((uint32_t)h) << 16);
}
// async global->LDS, 16 bytes per lane; LDS dest wave-uniform, global src per-lane.
static __device__ __forceinline__ void gll16(const ushort* g, ushort* l) {
    __builtin_amdgcn_global_load_lds(
        (const __attribute__((address_space(1))) uint32_t*)g,
        (__attribute__((address_space(3))) uint32_t*)l,
        16, 0, 0);
}
// raw barrier: lgkm-only wait, never drains in-flight vmem stores
static __device__ __forceinline__ void lgkm_barrier() {
    asm volatile("s_waitcnt lgkmcnt(0)" ::: "memory");
    __builtin_amdgcn_sched_barrier(0);
    __builtin_amdgcn_s_barrier();
    asm volatile("" ::: "memory");
}

// Kernel 1: fp32 -> bf16 in K-MAJOR PANEL layout xb[b][ks][t][j] (ks=e>>4,
// j=e&15), plus per-row sum of squares of the bf16-rounded values (distance
// diagonal cancels exactly against the fp32-accumulated MFMA gram).
__global__ void prep_kernel(const float* __restrict__ x,
                            ushort* __restrict__ xb,
                            float* __restrict__ sq) {
    __shared__ ushort sh[4][256];
    const int tid  = threadIdx.x;
    const int r    = tid >> 6;
    const int lane = tid & 63;
    const int grow = blockIdx.x * 4;
    const int row  = grow + r;

    const f32x4* xp = reinterpret_cast<const f32x4*>(x + (size_t)row * EDIM + lane * 4);
    const f32x4 v = __builtin_nontemporal_load(xp);
    ushort h0 = f2bf(v.x), h1 = f2bf(v.y), h2 = f2bf(v.z), h3 = f2bf(v.w);
    ushort4 h; h.x = h0; h.y = h1; h.z = h2; h.w = h3;
    *reinterpret_cast<ushort4*>(&sh[r][lane * 4]) = h;

    const float fx = bf2f(h0), fy = bf2f(h1), fz = bf2f(h2), fw = bf2f(h3);
    float s = fx * fx + fy * fy + fz * fz + fw * fw;
    #pragma unroll
    for (int m = 1; m < 64; m <<= 1) s += __shfl_xor(s, m);
    if (lane == 0) sq[row] = s;

    __syncthreads();

    const int b   = grow >> 11;
    const int t0  = grow & 2047;
    const int ksx = tid >> 4;
    const int idx = tid & 15;
    const int r2  = idx >> 2;
    const int j   = (idx & 3) * 4;
    ushort4 o = *reinterpret_cast<ushort4*>(&sh[r2][ksx * 16 + j]);
    *reinterpret_cast<ushort4*>(xb + (size_t)b * SEQ * EDIM
                                   + (size_t)ksx * SEQ * 16
                                   + (size_t)(t0 + r2) * 16 + j) = o;
}

// Kernel 2: fused gram-GEMM + one-pass softmax, 4 row-blocks per WG
// (R12 bf16 base = best known). Store phase restructured: epilogue deposits
// all 32 rows as bf16 into Tr32 (128 KB), ONE barrier, then each wave
// bursts its own 2 full rows (16 back-to-back plain dwordx4, 4 KB
// contiguous each). A-panel single-buffered, staged after the first
// epilogue barrier and BEFORE the burst, so block-top vmcnt(16) covers A
// while the 16 stores drain under the next K-loop. Laws honored: no stores
// in the K-loop (R8/R13), plain not nt (R12), counted vmcnt at block top.
__global__ __launch_bounds__(1024, 4) void sims_main(
        const ushort* __restrict__ xb,
        const float*  __restrict__ sq,
        float* __restrict__ out) {
    __shared__ __align__(16) ushort Ab[16 * 512];    // 16 KB A panel
    __shared__ __align__(16) ushort Tr32[32][2048];  // 128 KB bf16 out buffer
    __shared__ float red[32][17];
    __shared__ float inv_s[32];

    const int b    = blockIdx.x;        // batch -> XCD = flat%8 = b%8
    const int g    = blockIdx.y;        // rows [g*128,(g+1)*128)
    const int tid  = threadIdx.x;
    const int wave = tid >> 6;          // 0..15
    const int lane = tid & 63;
    const int l31  = lane & 31;
    const int hi   = lane >> 5;

    const ushort* xbB = xb + (size_t)b * SEQ * EDIM;
    const float*  sqB = sq + b * SEQ;
    float* outB = out + (size_t)b * SEQ * SEQ;

    const int colw = wave * 128;
    const ushort* bbase = xbB + ((size_t)colw + l31) * 16 + hi * 8;
    const int gl  = lane ^ ((lane >> 3) & 7);       // A-stage src chunk swizzle
    const int r6  = l31 * 2 + hi;
    const int pr6 = r6 ^ ((r6 >> 3) & 7);           // swizzled A read chunk

    constexpr float kC   = (float)(-1.4426950408889634 / 13.544);  // -log2(e)/T
    constexpr float m2kC = -2.0f * kC;
    float kcc[4];
    #pragma unroll
    for (int cb = 0; cb < 4; ++cb) kcc[cb] = kC * sqB[colw + cb * 32 + l31];

    // prologue: stage A panel for row-block 0
    gll16(xbB + (size_t)wave * (SEQ * 16) + ((g * 4 + 0) * 32 + (gl >> 1)) * 16 + (gl & 1) * 8,
          Ab + wave * 512);

    int prev_base = 0;
    const int row2base = 2 * wave;       // this wave bursts rows 2w, 2w+1

    #pragma unroll 1
    for (int rb = 0; rb < 4; ++rb) {
        // A panel ready; prev block's <=16 stores may stay in flight.
        if (rb == 0) { asm volatile("s_waitcnt vmcnt(0)" ::: "memory"); }
        else         { asm volatile("s_waitcnt vmcnt(16)" ::: "memory"); }
        __builtin_amdgcn_sched_barrier(0);
        __builtin_amdgcn_s_barrier();
        __builtin_amdgcn_sched_barrier(0);

        const int row_base = (g * 4 + rb) * 32;

        f32x16 acc[4];
        #pragma unroll
        for (int cb = 0; cb < 4; ++cb) acc[cb] = (f32x16)0.0f;

        #pragma unroll 2
        for (int ks = 0; ks < 16; ++ks) {
            const ushort* bks = bbase + (size_t)ks * (SEQ * 16);
            short8 bv[4];
            #pragma unroll
            for (int cb = 0; cb < 4; ++cb)
                bv[cb] = *reinterpret_cast<const short8*>(bks + cb * 512);
            const short8 a = *reinterpret_cast<const short8*>(Ab + ks * 512 + pr6 * 8);
            #pragma unroll
            for (int cb = 0; cb < 4; ++cb)
                acc[cb] = __builtin_amdgcn_mfma_f32_32x32x16_bf16(a, bv[cb], acc[cb], 0, 0, 0);
        }

        // ---- epilogue: exp(-dist/T), full-row sums ----
        float part[16];
        #pragma unroll
        for (int r = 0; r < 16; ++r) {
            const float kcr = kC * sqB[row_base + (r & 3) + 8 * (r >> 2) + 4 * hi];
            float p = 0.0f;
            #pragma unroll
            for (int cb = 0; cb < 4; ++cb) {
                const float e = exp2f(fmaf(m2kC, acc[cb][r], kcr + kcc[cb]));
                acc[cb][r] = e;
                p += e;
            }
            part[r] = p;
        }
        #pragma unroll
        for (int r = 0; r < 16; ++r) {
            float p = part[r];
            p += __shfl_xor(p, 1);
            p += __shfl_xor(p, 2);
            p += __shfl_xor(p, 4);
            p += __shfl_xor(p, 8);
            p += __shfl_xor(p, 16);
            part[r] = p;
        }
        if (l31 == 0) {
            #pragma unroll
            for (int r = 0; r < 16; ++r) {
                const int lrow = (r & 3) + 8 * (r >> 2) + 4 * hi;
                red[lrow][wave] = part[r];
            }
        }
        lgkm_barrier();                  // all waves past K-loop: Ab is free

        // stage next block's A panel now (before the store burst!)
        if (rb < 3) {
            gll16(xbB + (size_t)wave * (SEQ * 16)
                      + ((g * 4 + rb + 1) * 32 + (gl >> 1)) * 16 + (gl & 1) * 8,
                  Ab + wave * 512);
        }

        if (tid < 32) {
            float s = 0.0f;
            #pragma unroll
            for (int w = 0; w < 16; ++w) s += red[tid][w];
            inv_s[tid] = 1.0f / s;
        }
        lgkm_barrier();

        // ---- deposit: scale + bf16 into Tr32 (frees acc) ----
        #pragma unroll
        for (int r = 0; r < 16; ++r) {
            const int lrow = (r & 3) + 8 * (r >> 2) + 4 * hi;
            const float scale = inv_s[lrow];
            #pragma unroll
            for (int cb = 0; cb < 4; ++cb)
                Tr32[lrow][colw + cb * 32 + l31] = f2bf(acc[cb][r] * scale);
        }
        lgkm_barrier();                  // deposits visible to all waves

        // ---- burst: each wave stores its 2 full rows, 16 plain dwordx4 ----
        #pragma unroll
        for (int s = 0; s < 16; ++s) {
            const int row2 = row2base + (s >> 3);
            const int seg  = s & 7;
            const uint32_t* tp = reinterpret_cast<const uint32_t*>(
                &Tr32[row2][seg * 256 + lane * 4]);
            const uint32_t w01 = tp[0], w23 = tp[1];
            f32x4 v;
            v.x = __uint_as_float(w01 << 16);
            v.y = __uint_as_float(w01 & 0xffff0000u);
            v.z = __uint_as_float(w23 << 16);
            v.w = __uint_as_float(w23 & 0xffff0000u);
            *reinterpret_cast<f32x4*>(
                outB + (size_t)(row_base + row2) * SEQ + seg * 256 + lane * 4) = v;
        }
        prev_base = row_base;
    }
}

extern "C" void kernel_launch(void* const* d_in, const int* in_sizes, int n_in,
                              void* d_out, int out_size, void* d_ws, size_t ws_size,
                              hipStream_t stream) {
    (void)in_sizes; (void)n_in; (void)out_size; (void)ws_size;
    const float* x = (const float*)d_in[0];
    float* out = (float*)d_out;

    ushort* xb = (ushort*)d_ws;                                       // 16 MB bf16, k-major panels
    float*  sq = (float*)((char*)d_ws + (size_t)NB * SEQ * EDIM * 2); // 128 KB row norms

    prep_kernel<<<NB * SEQ / 4, 256, 0, stream>>>(x, xb, sq);

    dim3 grid(NB, 16);   // x = batch: flat%8 == batch%8 -> XCD locality; 256 WGs = 1/CU
    sims_main<<<grid, 1024, 0, stream>>>(xb, sq, out);
}